// Round 1
// baseline (777.888 us; speedup 1.0000x reference)
//
#include <hip/hip_runtime.h>

typedef unsigned short u16;
typedef unsigned int   u32;

using bf16x8 = __attribute__((ext_vector_type(8))) __bf16;
using f32x4  = __attribute__((ext_vector_type(4))) float;

#define EPS 1e-5f

__device__ __forceinline__ u16 f2bf(float f) {
  u32 u = __float_as_uint(f);
  u32 r = (u + 0x7FFFu + ((u >> 16) & 1u)) >> 16;
  return (u16)r;
}
__device__ __forceinline__ float bf2f(u16 h) {
  return __uint_as_float(((u32)h) << 16);
}

__device__ __forceinline__ void gload16(const void* g, void* l) {
  __builtin_amdgcn_global_load_lds((__attribute__((address_space(1))) void*)(void*)g,
                                   (__attribute__((address_space(3))) void*)l,
                                   16, 0, 0);
}

// 2-value block reduction (sum). Works for blockDim.x in {256, 512}.
__device__ __forceinline__ void blockReduce2(float& a, float& b, float* sm) {
  #pragma unroll
  for (int off = 32; off > 0; off >>= 1) {
    a += __shfl_down(a, off);
    b += __shfl_down(b, off);
  }
  const int w = threadIdx.x >> 6, l = threadIdx.x & 63;
  const int nw = blockDim.x >> 6;
  __syncthreads();
  if (l == 0) { sm[2*w] = a; sm[2*w+1] = b; }
  __syncthreads();
  a = sm[0]; b = sm[1];
  for (int i = 1; i < nw; ++i) { a += sm[2*i]; b += sm[2*i+1]; }
}

__device__ __forceinline__ float dot64(const float* __restrict__ w, const float* xs) {
  float s = 0.f;
  #pragma unroll
  for (int i = 0; i < 64; i += 4) {
    float4 wv = *(const float4*)(w + i);
    s = fmaf(wv.x, xs[i],   s);
    s = fmaf(wv.y, xs[i+1], s);
    s = fmaf(wv.z, xs[i+2], s);
    s = fmaf(wv.w, xs[i+3], s);
  }
  return s;
}

// ---- K0: zero the 63 left-pad rows per batch of xpad [4][1087][512] bf16
__global__ void k_zero_pad(u16* __restrict__ xpad) {
  const int b = blockIdx.x, row = blockIdx.y, t = threadIdx.x;
  const size_t base = ((size_t)(b*1087 + row)) << 9;
  xpad[base + t] = 0;
  xpad[base + t + 256] = 0;
}

// ---- K1: conv_w [O=512][I=512][K=64] f32 -> BT bf16 [O][K=64][I=512] (kk = k*512+i)
__global__ void k_cvt_w(const float* __restrict__ cw, u16* __restrict__ wt) {
  __shared__ float tile[128][65];
  const int o  = blockIdx.x;
  const int i0 = blockIdx.y << 7;
  const int tid = threadIdx.x;
  const size_t inBase = ((size_t)(o*512 + i0)) << 6;
  for (int idx = tid; idx < 128*64; idx += 256) {
    const int ii = idx >> 6, k = idx & 63;
    tile[ii][k] = cw[inBase + ((size_t)ii << 6) + k];
  }
  __syncthreads();
  const size_t outBase = ((size_t)o << 15) + i0;
  for (int idx = tid; idx < 128*64; idx += 256) {
    const int k = idx >> 7, ii = idx & 127;
    wt[outBase + ((size_t)k << 9) + ii] = f2bf(tile[ii][k]);
  }
}

// ---- K2: LN(x) -> xpad bf16 (one block per (b,t) row)
__global__ void k_ln_x(const float* __restrict__ x, const float* __restrict__ g,
                       const float* __restrict__ bta, u16* __restrict__ xpad) {
  __shared__ float sm[16];
  const int row = blockIdx.x;
  const int tid = threadIdx.x;
  const int e0 = tid, e1 = tid + 256;
  const size_t ib = (size_t)row << 9;
  const float v0 = x[ib + e0], v1 = x[ib + e1];
  float a = v0 + v1, b2 = v0*v0 + v1*v1;
  blockReduce2(a, b2, sm);
  const float mu = a * (1.f/512.f);
  const float var = b2 * (1.f/512.f) - mu*mu;
  const float rs = rsqrtf(var + EPS);
  const int bb = row >> 10, t = row & 1023;
  const size_t ob = ((size_t)(bb*1087 + 63 + t)) << 9;
  xpad[ob + e0] = f2bf((v0 - mu) * rs * g[e0] + bta[e0]);
  xpad[ob + e1] = f2bf((v1 - mu) * rs * g[e1] + bta[e1]);
}

// ---- K3: conv-as-GEMM, 128x128 tile, BK=64, split-K via blockIdx.z
__global__ __launch_bounds__(512) void k_gemm(
    const u16* __restrict__ wt, const u16* __restrict__ xpad,
    float* __restrict__ part, int kSteps)
{
  __shared__ __align__(16) u16 lsA[128*64];
  __shared__ __align__(16) u16 lsB[128*64];
  const int tid  = threadIdx.x;
  const int lane = tid & 63;
  const int wid  = tid >> 6;
  const int wm = wid >> 2, wn = wid & 3;   // 2 x 4 waves
  const int mb = blockIdx.x, nb = blockIdx.y, sp = blockIdx.z;

  // staging map: thread covers 16B at (row = tid>>3 [+64], colbyte = (tid&7)*16)
  const int srow = tid >> 3;
  const int scb  = (tid & 7) << 4;
  const int csrcE = (scb ^ ((srow & 7) << 4)) >> 1;  // pre-swizzled source col (elems)

  const int m0 = mb*128 + srow, m1 = m0 + 64;
  const int b0 = m0 >> 10, t0 = m0 & 1023;
  const int b1 = m1 >> 10, t1 = m1 & 1023;
  const u16* aB0 = xpad + (((size_t)(b0*1087 + t0)) << 9) + csrcE;
  const u16* aB1 = xpad + (((size_t)(b1*1087 + t1)) << 9) + csrcE;
  const u16* bB0 = wt + (((size_t)(nb*128 + srow)) << 15) + csrcE;
  const u16* bB1 = wt + (((size_t)(nb*128 + srow + 64)) << 15) + csrcE;
  u16* dA0 = &lsA[tid*8]; u16* dA1 = &lsA[4096 + tid*8];
  u16* dB0 = &lsB[tid*8]; u16* dB1 = &lsB[4096 + tid*8];

  const f32x4 zero4 = {0.f, 0.f, 0.f, 0.f};
  f32x4 acc[4][2];
  #pragma unroll
  for (int i = 0; i < 4; ++i)
    #pragma unroll
    for (int j = 0; j < 2; ++j) acc[i][j] = zero4;

  const int kBase = sp * kSteps;
  for (int kt = 0; kt < kSteps; ++kt) {
    const int ktg = kBase + kt;
    const int k  = ktg >> 3;
    const int i0 = (ktg & 7) << 6;
    const int aStep = (k << 9) + i0;
    gload16(aB0 + aStep, dA0);
    gload16(aB1 + aStep, dA1);
    gload16(bB0 + ((size_t)ktg << 6), dB0);
    gload16(bB1 + ((size_t)ktg << 6), dB1);
    __syncthreads();
    #pragma unroll
    for (int ks = 0; ks < 2; ++ks) {
      bf16x8 af[4], bv[2];
      #pragma unroll
      for (int mr = 0; mr < 4; ++mr) {
        const int r  = wm*64 + mr*16 + (lane & 15);
        const int cb = (ks << 6) + ((lane >> 4) << 4);
        af[mr] = *(const bf16x8*)((const char*)lsA + (r*128 + (cb ^ ((r & 7) << 4))));
      }
      #pragma unroll
      for (int nr = 0; nr < 2; ++nr) {
        const int r  = wn*32 + nr*16 + (lane & 15);
        const int cb = (ks << 6) + ((lane >> 4) << 4);
        bv[nr] = *(const bf16x8*)((const char*)lsB + (r*128 + (cb ^ ((r & 7) << 4))));
      }
      #pragma unroll
      for (int mr = 0; mr < 4; ++mr)
        #pragma unroll
        for (int nr = 0; nr < 2; ++nr)
          acc[mr][nr] = __builtin_amdgcn_mfma_f32_16x16x32_bf16(af[mr], bv[nr], acc[mr][nr], 0, 0, 0);
    }
    __syncthreads();
  }

  float* outp = part + ((size_t)sp * 4096) * 512;
  #pragma unroll
  for (int mr = 0; mr < 4; ++mr)
    #pragma unroll
    for (int nr = 0; nr < 2; ++nr)
      #pragma unroll
      for (int r4 = 0; r4 < 4; ++r4) {
        const int row = mb*128 + wm*64 + mr*16 + ((lane >> 4) << 2) + r4;
        const int col = nb*128 + wn*32 + nr*16 + (lane & 15);
        outp[((size_t)row << 9) + col] = acc[mr][nr][r4];
      }
}

// ---- K4: sum split-K partials + conv bias + silu -> x_conv (in-place into part[0])
__global__ void k_combine(float* __restrict__ part, const float* __restrict__ cb, int S) {
  const int n = 4096*512;
  for (int i = blockIdx.x*blockDim.x + threadIdx.x; i < n; i += gridDim.x*blockDim.x) {
    float v = part[i];
    for (int s = 1; s < S; ++s) v += part[(size_t)s*n + i];
    v += cb[i & 511];
    part[i] = v / (1.f + expf(-v));
  }
}

// ---- K4b: recurrent vectors rv[g][e] = bd(ht1, rw_g)[e]
__global__ void k_rvec(const float* __restrict__ rwi, const float* __restrict__ rwf,
                       const float* __restrict__ rwo, const float* __restrict__ rwz,
                       const float* __restrict__ ht1, float* __restrict__ rv) {
  const int tid = threadIdx.x;
  const float* w[4] = {rwi, rwf, rwo, rwz};
  for (int g = 0; g < 4; ++g)
    for (int e = tid; e < 512; e += 256) {
      const float* wr = w[g] + e*64;
      const float* hv = ht1 + (e >> 6)*64;
      float s = 0.f;
      for (int i = 0; i < 64; ++i) s = fmaf(wr[i], hv[i], s);
      rv[g*512 + e] = s;
    }
}

// ---- K5: gates + per-row LNs + ct/nt row-LN accumulation (8 rows/block)
__global__ __launch_bounds__(256) void k_gates(
    const float* __restrict__ xconv, const u16* __restrict__ xpad,
    const float* __restrict__ wi, const float* __restrict__ wf,
    const float* __restrict__ wo, const float* __restrict__ wz,
    const float* __restrict__ bi, const float* __restrict__ bf_,
    const float* __restrict__ bo, const float* __restrict__ bz,
    const float* __restrict__ rv,
    const float* __restrict__ lnig, const float* __restrict__ lnib,
    const float* __restrict__ lnfg, const float* __restrict__ lnfb,
    const float* __restrict__ lnog, const float* __restrict__ lnob,
    const float* __restrict__ lnzg, const float* __restrict__ lnzb,
    const float* __restrict__ lncg, const float* __restrict__ lncb,
    const float* __restrict__ lnng, const float* __restrict__ lnnb,
    const float* __restrict__ mt1, const float* __restrict__ ct1,
    const float* __restrict__ nt1,
    float* __restrict__ obuf, float* __restrict__ pct, float* __restrict__ pnt)
{
  __shared__ float xc[512], xl[512], sm[16];
  const int tid = threadIdx.x;
  const int e0 = tid, e1 = tid + 256;
  const int d0 = e0 >> 6, d1 = e1 >> 6;
  float aCt0 = 0.f, aCt1 = 0.f, aNt0 = 0.f, aNt1 = 0.f;
  const int rowBase = blockIdx.x * 8;
  for (int rr = 0; rr < 8; ++rr) {
    const int row = rowBase + rr;
    const size_t rb = (size_t)row << 9;
    const int bb = row >> 10, t = row & 1023;
    const size_t xb = ((size_t)(bb*1087 + 63 + t)) << 9;
    __syncthreads();
    xc[e0] = xconv[rb + e0]; xc[e1] = xconv[rb + e1];
    xl[e0] = bf2f(xpad[xb + e0]); xl[e1] = bf2f(xpad[xb + e1]);
    __syncthreads();
    const float gi0 = dot64(wi + e0*64, xc + d0*64) + bi[e0] + rv[e0];
    const float gi1 = dot64(wi + e1*64, xc + d1*64) + bi[e1] + rv[e1];
    const float gf0 = dot64(wf + e0*64, xc + d0*64) + bf_[e0] + rv[512 + e0];
    const float gf1 = dot64(wf + e1*64, xc + d1*64) + bf_[e1] + rv[512 + e1];
    const float go0 = dot64(wo + e0*64, xl + d0*64) + bo[e0] + rv[1024 + e0];
    const float go1 = dot64(wo + e1*64, xl + d1*64) + bo[e1] + rv[1024 + e1];
    const float gz0 = dot64(wz + e0*64, xl + d0*64) + bz[e0] + rv[1536 + e0];
    const float gz1 = dot64(wz + e1*64, xl + d1*64) + bz[e1] + rv[1536 + e1];

    float a, b2, mu, rs;
    a = gi0+gi1; b2 = gi0*gi0+gi1*gi1; blockReduce2(a, b2, sm);
    mu = a*(1.f/512.f); rs = rsqrtf(b2*(1.f/512.f) - mu*mu + EPS);
    const float li0 = (gi0-mu)*rs*lnig[e0]+lnib[e0], li1 = (gi1-mu)*rs*lnig[e1]+lnib[e1];
    a = gf0+gf1; b2 = gf0*gf0+gf1*gf1; blockReduce2(a, b2, sm);
    mu = a*(1.f/512.f); rs = rsqrtf(b2*(1.f/512.f) - mu*mu + EPS);
    const float lf0 = (gf0-mu)*rs*lnfg[e0]+lnfb[e0], lf1 = (gf1-mu)*rs*lnfg[e1]+lnfb[e1];
    a = go0+go1; b2 = go0*go0+go1*go1; blockReduce2(a, b2, sm);
    mu = a*(1.f/512.f); rs = rsqrtf(b2*(1.f/512.f) - mu*mu + EPS);
    const float o0 = 1.f/(1.f+expf(-((go0-mu)*rs*lnog[e0]+lnob[e0])));
    const float o1 = 1.f/(1.f+expf(-((go1-mu)*rs*lnog[e1]+lnob[e1])));
    a = gz0+gz1; b2 = gz0*gz0+gz1*gz1; blockReduce2(a, b2, sm);
    mu = a*(1.f/512.f); rs = rsqrtf(b2*(1.f/512.f) - mu*mu + EPS);
    const float z0 = tanhf((gz0-mu)*rs*lnzg[e0]+lnzb[e0]);
    const float z1 = tanhf((gz1-mu)*rs*lnzg[e1]+lnzb[e1]);

    obuf[rb + e0] = o0; obuf[rb + e1] = o1;

    const float mm0 = fmaxf(lf0 + mt1[e0], li0), mm1 = fmaxf(lf1 + mt1[e1], li1);
    const float iv0 = expf(li0 - mm0),  iv1 = expf(li1 - mm1);
    const float fv0 = expf(lf0 + mt1[e0] - mm0), fv1 = expf(lf1 + mt1[e1] - mm1);
    const float ctv0 = fv0*ct1[e0] + iv0*z0, ctv1 = fv1*ct1[e1] + iv1*z1;
    const float ntv0 = fv0*nt1[e0] + iv0,    ntv1 = fv1*nt1[e1] + iv1;

    a = ctv0+ctv1; b2 = ctv0*ctv0+ctv1*ctv1; blockReduce2(a, b2, sm);
    mu = a*(1.f/512.f); rs = rsqrtf(b2*(1.f/512.f) - mu*mu + EPS);
    aCt0 += (ctv0-mu)*rs*lncg[e0]+lncb[e0];
    aCt1 += (ctv1-mu)*rs*lncg[e1]+lncb[e1];
    a = ntv0+ntv1; b2 = ntv0*ntv0+ntv1*ntv1; blockReduce2(a, b2, sm);
    mu = a*(1.f/512.f); rs = rsqrtf(b2*(1.f/512.f) - mu*mu + EPS);
    aNt0 += (ntv0-mu)*rs*lnng[e0]+lnnb[e0];
    aNt1 += (ntv1-mu)*rs*lnng[e1]+lnnb[e1];
  }
  pct[(size_t)blockIdx.x*512 + e0] = aCt0; pct[(size_t)blockIdx.x*512 + e1] = aCt1;
  pnt[(size_t)blockIdx.x*512 + e0] = aNt0; pnt[(size_t)blockIdx.x*512 + e1] = aNt1;
}

// ---- K5b: r = sum(pct)/sum(pnt)
__global__ void k_r(const float* __restrict__ pct, const float* __restrict__ pnt,
                    float* __restrict__ rout) {
  const int e = threadIdx.x;
  float cs = 0.f, ns = 0.f;
  for (int b = 0; b < 512; ++b) { cs += pct[(size_t)b*512 + e]; ns += pnt[(size_t)b*512 + e]; }
  rout[e] = cs / ns;
}

// ---- K6: ht-row LN accumulation (8 rows/block)
__global__ __launch_bounds__(256) void k_ht(
    const float* __restrict__ obuf, const float* __restrict__ r,
    const float* __restrict__ lnhg, const float* __restrict__ lnhb,
    float* __restrict__ pht)
{
  __shared__ float sm[16];
  __shared__ float rsh[512];
  const int tid = threadIdx.x;
  const int e0 = tid, e1 = tid + 256;
  rsh[e0] = r[e0]; rsh[e1] = r[e1];
  __syncthreads();
  float acc0 = 0.f, acc1 = 0.f;
  const int rowBase = blockIdx.x*8;
  for (int rr = 0; rr < 8; ++rr) {
    const size_t rb = (size_t)(rowBase + rr) << 9;
    const float v0 = obuf[rb + e0]*rsh[e0], v1 = obuf[rb + e1]*rsh[e1];
    float a = v0+v1, b2 = v0*v0+v1*v1;
    blockReduce2(a, b2, sm);
    const float mu = a*(1.f/512.f), rs = rsqrtf(b2*(1.f/512.f)-mu*mu+EPS);
    acc0 += (v0-mu)*rs*lnhg[e0]+lnhb[e0];
    acc1 += (v1-mu)*rs*lnhg[e1]+lnhb[e1];
  }
  pht[(size_t)blockIdx.x*512 + e0] = acc0;
  pht[(size_t)blockIdx.x*512 + e1] = acc1;
}

// ---- K6b: htm mean + s = LN(htm, gn)
__global__ void k_s(const float* __restrict__ pht, const float* __restrict__ gng,
                    const float* __restrict__ gnb, float* __restrict__ svec) {
  __shared__ float sm[16];
  const int e = threadIdx.x;
  float hs = 0.f;
  for (int b = 0; b < 512; ++b) hs += pht[(size_t)b*512 + e];
  const float htm = hs * (1.f/4096.f);
  float a = htm, b2 = htm*htm;
  blockReduce2(a, b2, sm);
  const float mu = a*(1.f/512.f), rs = rsqrtf(b2*(1.f/512.f)-mu*mu+EPS);
  svec[e] = (htm-mu)*rs*gng[e]+gnb[e];
}

// ---- K7: lr[j] = (s.left_w[j]+lb)*gelu(s.right_w[j]+rb)
__global__ void k_lr(const float* __restrict__ svec,
                     const float* __restrict__ lw, const float* __restrict__ lb,
                     const float* __restrict__ rw, const float* __restrict__ rb_,
                     float* __restrict__ lr) {
  const int j = blockIdx.x, lane = threadIdx.x;
  const float* lwp = lw + (size_t)j*512;
  const float* rwp = rw + (size_t)j*512;
  float dl = 0.f, dr = 0.f;
  #pragma unroll
  for (int q = 0; q < 8; ++q) {
    const int e = lane*8 + q;
    dl = fmaf(lwp[e], svec[e], dl);
    dr = fmaf(rwp[e], svec[e], dr);
  }
  #pragma unroll
  for (int off = 32; off > 0; off >>= 1) { dl += __shfl_down(dl, off); dr += __shfl_down(dr, off); }
  if (lane == 0) {
    const float L = dl + lb[j];
    const float R = dr + rb_[j];
    const float gelu = 0.5f*R*(1.f + erff(R*0.70710678118654752440f));
    lr[j] = L * gelu;
  }
}

// ---- K8a: g = LN(lr, lnout)
__global__ void k_lnout(const float* __restrict__ lr, const float* __restrict__ lg,
                        const float* __restrict__ lb, float* __restrict__ gout) {
  __shared__ float sm[16];
  const int tid = threadIdx.x;
  float a = 0.f, b2 = 0.f;
  for (int j = tid; j < 682; j += 256) { const float v = lr[j]; a += v; b2 += v*v; }
  blockReduce2(a, b2, sm);
  const float mu = a*(1.f/682.f), rs = rsqrtf(b2*(1.f/682.f)-mu*mu+EPS);
  for (int j = tid; j < 682; j += 256) gout[j] = (lr[j]-mu)*rs*lg[j]+lb[j];
}

// ---- K8b: out[e] = g . proj_w[e] + proj_b[e]
__global__ void k_proj(const float* __restrict__ g, const float* __restrict__ pw,
                       const float* __restrict__ pb, float* __restrict__ out) {
  const int e = blockIdx.x, lane = threadIdx.x;
  const float* wp = pw + (size_t)e*682;
  float s = 0.f;
  for (int j = lane; j < 682; j += 64) s = fmaf(wp[j], g[j], s);
  #pragma unroll
  for (int off = 32; off > 0; off >>= 1) s += __shfl_down(s, off);
  if (lane == 0) out[e] = s + pb[e];
}

extern "C" void kernel_launch(void* const* d_in, const int* in_sizes, int n_in,
                              void* d_out, int out_size, void* d_ws, size_t ws_size,
                              hipStream_t stream) {
  const float* x      = (const float*)d_in[0];
  const float* conv_w = (const float*)d_in[1];
  const float* conv_b = (const float*)d_in[2];
  const float* wi  = (const float*)d_in[3];
  const float* wf  = (const float*)d_in[4];
  const float* wo  = (const float*)d_in[5];
  const float* wz  = (const float*)d_in[6];
  const float* rwi = (const float*)d_in[7];
  const float* rwf = (const float*)d_in[8];
  const float* rwo = (const float*)d_in[9];
  const float* rwz = (const float*)d_in[10];
  const float* bi  = (const float*)d_in[11];
  const float* bf  = (const float*)d_in[12];
  const float* bo  = (const float*)d_in[13];
  const float* bz  = (const float*)d_in[14];
  const float* ln_g  = (const float*)d_in[15];
  const float* ln_b  = (const float*)d_in[16];
  const float* lni_g = (const float*)d_in[17];
  const float* lni_b = (const float*)d_in[18];
  const float* lnf_g = (const float*)d_in[19];
  const float* lnf_b = (const float*)d_in[20];
  const float* lno_g = (const float*)d_in[21];
  const float* lno_b = (const float*)d_in[22];
  const float* lnz_g = (const float*)d_in[23];
  const float* lnz_b = (const float*)d_in[24];
  const float* gn_g  = (const float*)d_in[25];
  const float* gn_b  = (const float*)d_in[26];
  const float* lnc_g = (const float*)d_in[27];
  const float* lnc_b = (const float*)d_in[28];
  const float* lnn_g = (const float*)d_in[29];
  const float* lnn_b = (const float*)d_in[30];
  const float* lnh_g = (const float*)d_in[31];
  const float* lnh_b = (const float*)d_in[32];
  const float* left_w  = (const float*)d_in[33];
  const float* left_b  = (const float*)d_in[34];
  const float* right_w = (const float*)d_in[35];
  const float* right_b = (const float*)d_in[36];
  const float* lnout_g = (const float*)d_in[37];
  const float* lnout_b = (const float*)d_in[38];
  const float* proj_w  = (const float*)d_in[39];
  const float* proj_b  = (const float*)d_in[40];
  const float* nt1 = (const float*)d_in[41];
  const float* ct1 = (const float*)d_in[42];
  const float* ht1 = (const float*)d_in[43];
  const float* mt1 = (const float*)d_in[44];
  float* dout = (float*)d_out;

  char* ws = (char*)d_ws;
  size_t off = 0;
  auto alloc = [&](size_t n) { size_t o = off; off += (n + 255) & ~(size_t)255; return o; };

  const size_t SZ_WT   = 512ull*32768*2;   // 32 MB
  const size_t SZ_XPAD = 4ull*1087*512*2;  // 4.45 MB
  const size_t SZ_PART = 4096ull*512*4;    // 8 MB per split
  const size_t tail = (4*512*4 + 256) + 3*(512*512*4 + 256) + 6*4096;
  int S = (SZ_WT + SZ_XPAD + 4*SZ_PART + tail + 65536 <= ws_size) ? 4 : 2;

  const size_t o_wt   = alloc(SZ_WT);
  const size_t o_xpad = alloc(SZ_XPAD);
  const size_t o_part = alloc((size_t)S * SZ_PART);
  const size_t o_rv   = alloc(4*512*4);
  const size_t o_pct  = alloc(512*512*4);
  const size_t o_pnt  = alloc(512*512*4);
  const size_t o_pht  = alloc(512*512*4);
  const size_t o_r    = alloc(512*4);
  const size_t o_s    = alloc(512*4);
  const size_t o_lr   = alloc(682*4);
  const size_t o_g    = alloc(682*4);

  u16*   wt    = (u16*)(ws + o_wt);
  u16*   xpad  = (u16*)(ws + o_xpad);
  float* part  = (float*)(ws + o_part);
  float* xconv = part;                         // aliases part[0] after k_combine
  float* obuf  = part + (size_t)4096*512;      // aliases part[1] after k_combine
  float* rv    = (float*)(ws + o_rv);
  float* pct   = (float*)(ws + o_pct);
  float* pnt   = (float*)(ws + o_pnt);
  float* pht   = (float*)(ws + o_pht);
  float* rbuf  = (float*)(ws + o_r);
  float* svec  = (float*)(ws + o_s);
  float* lrbuf = (float*)(ws + o_lr);
  float* gbuf  = (float*)(ws + o_g);

  k_zero_pad<<<dim3(4, 63), 256, 0, stream>>>(xpad);
  k_cvt_w<<<dim3(512, 4), 256, 0, stream>>>(conv_w, wt);
  k_ln_x<<<4096, 256, 0, stream>>>(x, ln_g, ln_b, xpad);
  k_gemm<<<dim3(32, 4, S), 512, 0, stream>>>(wt, xpad, part, 512 / S);
  k_combine<<<2048, 256, 0, stream>>>(part, conv_b, S);
  k_rvec<<<1, 256, 0, stream>>>(rwi, rwf, rwo, rwz, ht1, rv);
  k_gates<<<512, 256, 0, stream>>>(xconv, xpad,
      wi, wf, wo, wz, bi, bf, bo, bz, rv,
      lni_g, lni_b, lnf_g, lnf_b, lno_g, lno_b, lnz_g, lnz_b,
      lnc_g, lnc_b, lnn_g, lnn_b, mt1, ct1, nt1,
      obuf, pct, pnt);
  k_r<<<1, 512, 0, stream>>>(pct, pnt, rbuf);
  k_ht<<<512, 256, 0, stream>>>(obuf, rbuf, lnh_g, lnh_b, pht);
  k_s<<<1, 512, 0, stream>>>(pht, gn_g, gn_b, svec);
  k_lr<<<682, 64, 0, stream>>>(svec, left_w, left_b, right_w, right_b, lrbuf);
  k_lnout<<<1, 256, 0, stream>>>(lrbuf, lnout_g, lnout_b, gbuf);
  k_proj<<<512, 64, 0, stream>>>(gbuf, proj_w, proj_b, dout);
}

// Round 2
// 308.224 us; speedup vs baseline: 2.5238x; 2.5238x over previous
//
#include <hip/hip_runtime.h>

typedef unsigned short u16;
typedef unsigned int   u32;

using bf16x8 = __attribute__((ext_vector_type(8))) __bf16;
using f32x4  = __attribute__((ext_vector_type(4))) float;

#define EPS 1e-5f

__device__ __forceinline__ u16 f2bf(float f) {
  u32 u = __float_as_uint(f);
  u32 r = (u + 0x7FFFu + ((u >> 16) & 1u)) >> 16;
  return (u16)r;
}
__device__ __forceinline__ float bf2f(u16 h) {
  return __uint_as_float(((u32)h) << 16);
}

__device__ __forceinline__ void gload16(const void* g, void* l) {
  __builtin_amdgcn_global_load_lds((__attribute__((address_space(1))) void*)(void*)g,
                                   (__attribute__((address_space(3))) void*)l,
                                   16, 0, 0);
}

// 2-value block reduction (sum). Works for blockDim.x in {256, 512}.
__device__ __forceinline__ void blockReduce2(float& a, float& b, float* sm) {
  #pragma unroll
  for (int off = 32; off > 0; off >>= 1) {
    a += __shfl_down(a, off);
    b += __shfl_down(b, off);
  }
  const int w = threadIdx.x >> 6, l = threadIdx.x & 63;
  const int nw = blockDim.x >> 6;
  __syncthreads();
  if (l == 0) { sm[2*w] = a; sm[2*w+1] = b; }
  __syncthreads();
  a = sm[0]; b = sm[1];
  for (int i = 1; i < nw; ++i) { a += sm[2*i]; b += sm[2*i+1]; }
}

// ---- K0: zero the 63 left-pad rows per batch of xpad [4][1087][512] bf16
__global__ void k_zero_pad(u16* __restrict__ xpad) {
  const int b = blockIdx.x, row = blockIdx.y, t = threadIdx.x;
  const size_t base = ((size_t)(b*1087 + row)) << 9;
  xpad[base + t] = 0;
  xpad[base + t + 256] = 0;
}

// ---- K1: conv_w [O=512][I=512][K=64] f32 -> BT bf16 [O][K=64][I=512] (kk = k*512+i)
__global__ void k_cvt_w(const float* __restrict__ cw, u16* __restrict__ wt) {
  __shared__ float tile[128][65];
  const int o  = blockIdx.x;
  const int i0 = blockIdx.y << 7;
  const int tid = threadIdx.x;
  const size_t inBase = ((size_t)(o*512 + i0)) << 6;
  for (int idx = tid; idx < 128*64; idx += 256) {
    const int ii = idx >> 6, k = idx & 63;
    tile[ii][k] = cw[inBase + ((size_t)ii << 6) + k];
  }
  __syncthreads();
  const size_t outBase = ((size_t)o << 15) + i0;
  for (int idx = tid; idx < 128*64; idx += 256) {
    const int k = idx >> 7, ii = idx & 127;
    wt[outBase + ((size_t)k << 9) + ii] = f2bf(tile[ii][k]);
  }
}

// ---- K2: LN(x) -> xpad bf16 (one block per (b,t) row)
__global__ void k_ln_x(const float* __restrict__ x, const float* __restrict__ g,
                       const float* __restrict__ bta, u16* __restrict__ xpad) {
  __shared__ float sm[16];
  const int row = blockIdx.x;
  const int tid = threadIdx.x;
  const int e0 = tid, e1 = tid + 256;
  const size_t ib = (size_t)row << 9;
  const float v0 = x[ib + e0], v1 = x[ib + e1];
  float a = v0 + v1, b2 = v0*v0 + v1*v1;
  blockReduce2(a, b2, sm);
  const float mu = a * (1.f/512.f);
  const float var = b2 * (1.f/512.f) - mu*mu;
  const float rs = rsqrtf(var + EPS);
  const int bb = row >> 10, t = row & 1023;
  const size_t ob = ((size_t)(bb*1087 + 63 + t)) << 9;
  xpad[ob + e0] = f2bf((v0 - mu) * rs * g[e0] + bta[e0]);
  xpad[ob + e1] = f2bf((v1 - mu) * rs * g[e1] + bta[e1]);
}

// ---- K3: conv-as-GEMM, 128x128 tile, BK=64, split-K via blockIdx.z
__global__ __launch_bounds__(512) void k_gemm(
    const u16* __restrict__ wt, const u16* __restrict__ xpad,
    float* __restrict__ part, int kSteps)
{
  __shared__ __align__(16) u16 lsA[128*64];
  __shared__ __align__(16) u16 lsB[128*64];
  const int tid  = threadIdx.x;
  const int lane = tid & 63;
  const int wid  = tid >> 6;
  const int wm = wid >> 2, wn = wid & 3;   // 2 x 4 waves
  const int mb = blockIdx.x, nb = blockIdx.y, sp = blockIdx.z;

  // staging map: thread covers 16B at (row = tid>>3 [+64], colbyte = (tid&7)*16)
  const int srow = tid >> 3;
  const int scb  = (tid & 7) << 4;
  const int csrcE = (scb ^ ((srow & 7) << 4)) >> 1;  // pre-swizzled source col (elems)

  const int m0 = mb*128 + srow, m1 = m0 + 64;
  const int b0 = m0 >> 10, t0 = m0 & 1023;
  const int b1 = m1 >> 10, t1 = m1 & 1023;
  const u16* aB0 = xpad + (((size_t)(b0*1087 + t0)) << 9) + csrcE;
  const u16* aB1 = xpad + (((size_t)(b1*1087 + t1)) << 9) + csrcE;
  const u16* bB0 = wt + (((size_t)(nb*128 + srow)) << 15) + csrcE;
  const u16* bB1 = wt + (((size_t)(nb*128 + srow + 64)) << 15) + csrcE;
  u16* dA0 = &lsA[tid*8]; u16* dA1 = &lsA[4096 + tid*8];
  u16* dB0 = &lsB[tid*8]; u16* dB1 = &lsB[4096 + tid*8];

  const f32x4 zero4 = {0.f, 0.f, 0.f, 0.f};
  f32x4 acc[4][2];
  #pragma unroll
  for (int i = 0; i < 4; ++i)
    #pragma unroll
    for (int j = 0; j < 2; ++j) acc[i][j] = zero4;

  const int kBase = sp * kSteps;
  for (int kt = 0; kt < kSteps; ++kt) {
    const int ktg = kBase + kt;
    const int k  = ktg >> 3;
    const int i0 = (ktg & 7) << 6;
    const int aStep = (k << 9) + i0;
    gload16(aB0 + aStep, dA0);
    gload16(aB1 + aStep, dA1);
    gload16(bB0 + ((size_t)ktg << 6), dB0);
    gload16(bB1 + ((size_t)ktg << 6), dB1);
    __syncthreads();
    #pragma unroll
    for (int ks = 0; ks < 2; ++ks) {
      bf16x8 af[4], bv[2];
      #pragma unroll
      for (int mr = 0; mr < 4; ++mr) {
        const int r  = wm*64 + mr*16 + (lane & 15);
        const int cb = (ks << 6) + ((lane >> 4) << 4);
        af[mr] = *(const bf16x8*)((const char*)lsA + (r*128 + (cb ^ ((r & 7) << 4))));
      }
      #pragma unroll
      for (int nr = 0; nr < 2; ++nr) {
        const int r  = wn*32 + nr*16 + (lane & 15);
        const int cb = (ks << 6) + ((lane >> 4) << 4);
        bv[nr] = *(const bf16x8*)((const char*)lsB + (r*128 + (cb ^ ((r & 7) << 4))));
      }
      #pragma unroll
      for (int mr = 0; mr < 4; ++mr)
        #pragma unroll
        for (int nr = 0; nr < 2; ++nr)
          acc[mr][nr] = __builtin_amdgcn_mfma_f32_16x16x32_bf16(af[mr], bv[nr], acc[mr][nr], 0, 0, 0);
    }
    __syncthreads();
  }

  float* outp = part + ((size_t)sp * 4096) * 512;
  #pragma unroll
  for (int mr = 0; mr < 4; ++mr)
    #pragma unroll
    for (int nr = 0; nr < 2; ++nr)
      #pragma unroll
      for (int r4 = 0; r4 < 4; ++r4) {
        const int row = mb*128 + wm*64 + mr*16 + ((lane >> 4) << 2) + r4;
        const int col = nb*128 + wn*32 + nr*16 + (lane & 15);
        outp[((size_t)row << 9) + col] = acc[mr][nr][r4];
      }
}

// ---- K4b: recurrent vectors rv[g][e] = bd(ht1, rw_g)[e]
__global__ void k_rvec(const float* __restrict__ rwi, const float* __restrict__ rwf,
                       const float* __restrict__ rwo, const float* __restrict__ rwz,
                       const float* __restrict__ ht1, float* __restrict__ rv) {
  const int tid = threadIdx.x;
  const float* w[4] = {rwi, rwf, rwo, rwz};
  for (int g = 0; g < 4; ++g)
    for (int e = tid; e < 512; e += 256) {
      const float* wr = w[g] + e*64;
      const float* hv = ht1 + (e >> 6)*64;
      float s = 0.f;
      for (int i = 0; i < 64; ++i) s = fmaf(wr[i], hv[i], s);
      rv[g*512 + e] = s;
    }
}

// ---- K5a: block-diagonal gate pre-activations, weights in LDS.
// grid (d=8, rowchunk=64, gpair=2), 256 thr. gpair0: gates i,f from silu(conv);
// gpair1: gates o,z from x_ln. Fuses split-K combine + bias + silu for its slice.
// pre[g][4096][512], g: 0=i 1=f 2=o 3=z.
__global__ __launch_bounds__(256) void k_bd(
    const float* __restrict__ part, int S,
    const float* __restrict__ cb, const u16* __restrict__ xpad,
    const float* __restrict__ wi, const float* __restrict__ wf,
    const float* __restrict__ wo, const float* __restrict__ wz,
    const float* __restrict__ bi, const float* __restrict__ bf_,
    const float* __restrict__ bo, const float* __restrict__ bz,
    const float* __restrict__ rv,
    float* __restrict__ pre)
{
  __shared__ float wT[2*64*65];   // [g][i][o], +1 pad
  __shared__ float xs[64*64];     // [r][i]
  const int d  = blockIdx.x;
  const int rc = blockIdx.y;
  const int gp = blockIdx.z;
  const int t  = threadIdx.x;
  const size_t N = 4096ull*512;

  const float* w0 = gp ? wo : wi;
  const float* w1 = gp ? wz : wf;
  const float* bb0 = gp ? bo : bi;
  const float* bb1 = gp ? bz : bf_;

  // load + transpose weights: w[d][o][i] -> wT[g][i*65+o]
  for (int idx = t; idx < 4096; idx += 256) {
    const int o = idx >> 6, i = idx & 63;
    wT[i*65 + o]        = w0[d*4096 + idx];
    wT[4160 + i*65 + o] = w1[d*4096 + idx];
  }
  // stage x slice [64 rows][64 cols]
  for (int idx = t; idx < 4096; idx += 256) {
    const int r = idx >> 6, i = idx & 63;
    const int row = rc*64 + r;
    const int col = d*64 + i;
    float v;
    if (gp == 0) {
      v = cb[col];
      for (int s = 0; s < S; ++s) v += part[(size_t)s*N + (size_t)row*512 + col];
      v = v / (1.f + expf(-v));           // silu(conv+bias)
    } else {
      const int bq = row >> 10, tt = row & 1023;
      v = bf2f(xpad[(((size_t)(bq*1087 + 63 + tt)) << 9) + col]);
    }
    xs[idx] = v;
  }
  __syncthreads();

  const int o  = t & 63;
  const int rg = t >> 6;          // 0..3, rows rg*16..rg*16+15
  const int e  = d*64 + o;
  const float bias0 = bb0[e] + rv[(gp*2+0)*512 + e];
  const float bias1 = bb1[e] + rv[(gp*2+1)*512 + e];

  float acc0[16], acc1[16];
  #pragma unroll
  for (int rr = 0; rr < 16; ++rr) { acc0[rr] = 0.f; acc1[rr] = 0.f; }

  for (int i = 0; i < 64; ++i) {
    const float w0v = wT[i*65 + o];
    const float w1v = wT[4160 + i*65 + o];
    const float* xr = xs + rg*16*64 + i;
    #pragma unroll
    for (int rr = 0; rr < 16; ++rr) {
      const float xv = xr[rr*64];
      acc0[rr] = fmaf(xv, w0v, acc0[rr]);
      acc1[rr] = fmaf(xv, w1v, acc1[rr]);
    }
  }

  float* p0 = pre + (size_t)(gp*2+0)*N;
  float* p1 = pre + (size_t)(gp*2+1)*N;
  #pragma unroll
  for (int rr = 0; rr < 16; ++rr) {
    const size_t row = rc*64 + rg*16 + rr;
    p0[row*512 + e] = acc0[rr] + bias0;
    p1[row*512 + e] = acc1[rr] + bias1;
  }
}

// ---- K5: per-row LNs + gating + ct/nt row-LN accumulation (8 rows/block)
__global__ __launch_bounds__(256) void k_gates2(
    const float* __restrict__ pre,
    const float* __restrict__ lnig, const float* __restrict__ lnib,
    const float* __restrict__ lnfg, const float* __restrict__ lnfb,
    const float* __restrict__ lnog, const float* __restrict__ lnob,
    const float* __restrict__ lnzg, const float* __restrict__ lnzb,
    const float* __restrict__ lncg, const float* __restrict__ lncb,
    const float* __restrict__ lnng, const float* __restrict__ lnnb,
    const float* __restrict__ mt1, const float* __restrict__ ct1,
    const float* __restrict__ nt1,
    float* __restrict__ obuf, float* __restrict__ pct, float* __restrict__ pnt)
{
  __shared__ float sm[16];
  const size_t N = 4096ull*512;
  const int tid = threadIdx.x;
  const int e0 = tid, e1 = tid + 256;
  float aCt0 = 0.f, aCt1 = 0.f, aNt0 = 0.f, aNt1 = 0.f;
  const int rowBase = blockIdx.x * 8;
  for (int rr = 0; rr < 8; ++rr) {
    const int row = rowBase + rr;
    const size_t rb = (size_t)row << 9;
    const float gi0 = pre[rb + e0],       gi1 = pre[rb + e1];
    const float gf0 = pre[N + rb + e0],   gf1 = pre[N + rb + e1];
    const float go0 = pre[2*N + rb + e0], go1 = pre[2*N + rb + e1];
    const float gz0 = pre[3*N + rb + e0], gz1 = pre[3*N + rb + e1];

    float a, b2, mu, rs;
    a = gi0+gi1; b2 = gi0*gi0+gi1*gi1; blockReduce2(a, b2, sm);
    mu = a*(1.f/512.f); rs = rsqrtf(b2*(1.f/512.f) - mu*mu + EPS);
    const float li0 = (gi0-mu)*rs*lnig[e0]+lnib[e0], li1 = (gi1-mu)*rs*lnig[e1]+lnib[e1];
    a = gf0+gf1; b2 = gf0*gf0+gf1*gf1; blockReduce2(a, b2, sm);
    mu = a*(1.f/512.f); rs = rsqrtf(b2*(1.f/512.f) - mu*mu + EPS);
    const float lf0 = (gf0-mu)*rs*lnfg[e0]+lnfb[e0], lf1 = (gf1-mu)*rs*lnfg[e1]+lnfb[e1];
    a = go0+go1; b2 = go0*go0+go1*go1; blockReduce2(a, b2, sm);
    mu = a*(1.f/512.f); rs = rsqrtf(b2*(1.f/512.f) - mu*mu + EPS);
    const float o0 = 1.f/(1.f+expf(-((go0-mu)*rs*lnog[e0]+lnob[e0])));
    const float o1 = 1.f/(1.f+expf(-((go1-mu)*rs*lnog[e1]+lnob[e1])));
    a = gz0+gz1; b2 = gz0*gz0+gz1*gz1; blockReduce2(a, b2, sm);
    mu = a*(1.f/512.f); rs = rsqrtf(b2*(1.f/512.f) - mu*mu + EPS);
    const float z0 = tanhf((gz0-mu)*rs*lnzg[e0]+lnzb[e0]);
    const float z1 = tanhf((gz1-mu)*rs*lnzg[e1]+lnzb[e1]);

    obuf[rb + e0] = o0; obuf[rb + e1] = o1;

    const float mm0 = fmaxf(lf0 + mt1[e0], li0), mm1 = fmaxf(lf1 + mt1[e1], li1);
    const float iv0 = expf(li0 - mm0),  iv1 = expf(li1 - mm1);
    const float fv0 = expf(lf0 + mt1[e0] - mm0), fv1 = expf(lf1 + mt1[e1] - mm1);
    const float ctv0 = fv0*ct1[e0] + iv0*z0, ctv1 = fv1*ct1[e1] + iv1*z1;
    const float ntv0 = fv0*nt1[e0] + iv0,    ntv1 = fv1*nt1[e1] + iv1;

    a = ctv0+ctv1; b2 = ctv0*ctv0+ctv1*ctv1; blockReduce2(a, b2, sm);
    mu = a*(1.f/512.f); rs = rsqrtf(b2*(1.f/512.f) - mu*mu + EPS);
    aCt0 += (ctv0-mu)*rs*lncg[e0]+lncb[e0];
    aCt1 += (ctv1-mu)*rs*lncg[e1]+lncb[e1];
    a = ntv0+ntv1; b2 = ntv0*ntv0+ntv1*ntv1; blockReduce2(a, b2, sm);
    mu = a*(1.f/512.f); rs = rsqrtf(b2*(1.f/512.f) - mu*mu + EPS);
    aNt0 += (ntv0-mu)*rs*lnng[e0]+lnnb[e0];
    aNt1 += (ntv1-mu)*rs*lnng[e1]+lnnb[e1];
  }
  pct[(size_t)blockIdx.x*512 + e0] = aCt0; pct[(size_t)blockIdx.x*512 + e1] = aCt1;
  pnt[(size_t)blockIdx.x*512 + e0] = aNt0; pnt[(size_t)blockIdx.x*512 + e1] = aNt1;
}

// ---- K5b: r = sum(pct)/sum(pnt)
__global__ void k_r(const float* __restrict__ pct, const float* __restrict__ pnt,
                    float* __restrict__ rout) {
  const int e = threadIdx.x;
  float cs = 0.f, ns = 0.f;
  for (int b = 0; b < 512; ++b) { cs += pct[(size_t)b*512 + e]; ns += pnt[(size_t)b*512 + e]; }
  rout[e] = cs / ns;
}

// ---- K6: ht-row LN accumulation (8 rows/block)
__global__ __launch_bounds__(256) void k_ht(
    const float* __restrict__ obuf, const float* __restrict__ r,
    const float* __restrict__ lnhg, const float* __restrict__ lnhb,
    float* __restrict__ pht)
{
  __shared__ float sm[16];
  __shared__ float rsh[512];
  const int tid = threadIdx.x;
  const int e0 = tid, e1 = tid + 256;
  rsh[e0] = r[e0]; rsh[e1] = r[e1];
  __syncthreads();
  float acc0 = 0.f, acc1 = 0.f;
  const int rowBase = blockIdx.x*8;
  for (int rr = 0; rr < 8; ++rr) {
    const size_t rb = (size_t)(rowBase + rr) << 9;
    const float v0 = obuf[rb + e0]*rsh[e0], v1 = obuf[rb + e1]*rsh[e1];
    float a = v0+v1, b2 = v0*v0+v1*v1;
    blockReduce2(a, b2, sm);
    const float mu = a*(1.f/512.f), rs = rsqrtf(b2*(1.f/512.f)-mu*mu+EPS);
    acc0 += (v0-mu)*rs*lnhg[e0]+lnhb[e0];
    acc1 += (v1-mu)*rs*lnhg[e1]+lnhb[e1];
  }
  pht[(size_t)blockIdx.x*512 + e0] = acc0;
  pht[(size_t)blockIdx.x*512 + e1] = acc1;
}

// ---- K6b: htm mean + s = LN(htm, gn)
__global__ void k_s(const float* __restrict__ pht, const float* __restrict__ gng,
                    const float* __restrict__ gnb, float* __restrict__ svec) {
  __shared__ float sm[16];
  const int e = threadIdx.x;
  float hs = 0.f;
  for (int b = 0; b < 512; ++b) hs += pht[(size_t)b*512 + e];
  const float htm = hs * (1.f/4096.f);
  float a = htm, b2 = htm*htm;
  blockReduce2(a, b2, sm);
  const float mu = a*(1.f/512.f), rs = rsqrtf(b2*(1.f/512.f)-mu*mu+EPS);
  svec[e] = (htm-mu)*rs*gng[e]+gnb[e];
}

// ---- K7: lr[j] = (s.left_w[j]+lb)*gelu(s.right_w[j]+rb)
__global__ void k_lr(const float* __restrict__ svec,
                     const float* __restrict__ lw, const float* __restrict__ lb,
                     const float* __restrict__ rw, const float* __restrict__ rb_,
                     float* __restrict__ lr) {
  const int j = blockIdx.x, lane = threadIdx.x;
  const float* lwp = lw + (size_t)j*512;
  const float* rwp = rw + (size_t)j*512;
  float dl = 0.f, dr = 0.f;
  #pragma unroll
  for (int q = 0; q < 8; ++q) {
    const int e = lane*8 + q;
    dl = fmaf(lwp[e], svec[e], dl);
    dr = fmaf(rwp[e], svec[e], dr);
  }
  #pragma unroll
  for (int off = 32; off > 0; off >>= 1) { dl += __shfl_down(dl, off); dr += __shfl_down(dr, off); }
  if (lane == 0) {
    const float L = dl + lb[j];
    const float R = dr + rb_[j];
    const float gelu = 0.5f*R*(1.f + erff(R*0.70710678118654752440f));
    lr[j] = L * gelu;
  }
}

// ---- K8a: g = LN(lr, lnout)
__global__ void k_lnout(const float* __restrict__ lr, const float* __restrict__ lg,
                        const float* __restrict__ lb, float* __restrict__ gout) {
  __shared__ float sm[16];
  const int tid = threadIdx.x;
  float a = 0.f, b2 = 0.f;
  for (int j = tid; j < 682; j += 256) { const float v = lr[j]; a += v; b2 += v*v; }
  blockReduce2(a, b2, sm);
  const float mu = a*(1.f/682.f), rs = rsqrtf(b2*(1.f/682.f)-mu*mu+EPS);
  for (int j = tid; j < 682; j += 256) gout[j] = (lr[j]-mu)*rs*lg[j]+lb[j];
}

// ---- K8b: out[e] = g . proj_w[e] + proj_b[e]
__global__ void k_proj(const float* __restrict__ g, const float* __restrict__ pw,
                       const float* __restrict__ pb, float* __restrict__ out) {
  const int e = blockIdx.x, lane = threadIdx.x;
  const float* wp = pw + (size_t)e*682;
  float s = 0.f;
  for (int j = lane; j < 682; j += 64) s = fmaf(wp[j], g[j], s);
  #pragma unroll
  for (int off = 32; off > 0; off >>= 1) s += __shfl_down(s, off);
  if (lane == 0) out[e] = s + pb[e];
}

extern "C" void kernel_launch(void* const* d_in, const int* in_sizes, int n_in,
                              void* d_out, int out_size, void* d_ws, size_t ws_size,
                              hipStream_t stream) {
  const float* x      = (const float*)d_in[0];
  const float* conv_w = (const float*)d_in[1];
  const float* conv_b = (const float*)d_in[2];
  const float* wi  = (const float*)d_in[3];
  const float* wf  = (const float*)d_in[4];
  const float* wo  = (const float*)d_in[5];
  const float* wz  = (const float*)d_in[6];
  const float* rwi = (const float*)d_in[7];
  const float* rwf = (const float*)d_in[8];
  const float* rwo = (const float*)d_in[9];
  const float* rwz = (const float*)d_in[10];
  const float* bi  = (const float*)d_in[11];
  const float* bf  = (const float*)d_in[12];
  const float* bo  = (const float*)d_in[13];
  const float* bz  = (const float*)d_in[14];
  const float* ln_g  = (const float*)d_in[15];
  const float* ln_b  = (const float*)d_in[16];
  const float* lni_g = (const float*)d_in[17];
  const float* lni_b = (const float*)d_in[18];
  const float* lnf_g = (const float*)d_in[19];
  const float* lnf_b = (const float*)d_in[20];
  const float* lno_g = (const float*)d_in[21];
  const float* lno_b = (const float*)d_in[22];
  const float* lnz_g = (const float*)d_in[23];
  const float* lnz_b = (const float*)d_in[24];
  const float* gn_g  = (const float*)d_in[25];
  const float* gn_b  = (const float*)d_in[26];
  const float* lnc_g = (const float*)d_in[27];
  const float* lnc_b = (const float*)d_in[28];
  const float* lnn_g = (const float*)d_in[29];
  const float* lnn_b = (const float*)d_in[30];
  const float* lnh_g = (const float*)d_in[31];
  const float* lnh_b = (const float*)d_in[32];
  const float* left_w  = (const float*)d_in[33];
  const float* left_b  = (const float*)d_in[34];
  const float* right_w = (const float*)d_in[35];
  const float* right_b = (const float*)d_in[36];
  const float* lnout_g = (const float*)d_in[37];
  const float* lnout_b = (const float*)d_in[38];
  const float* proj_w  = (const float*)d_in[39];
  const float* proj_b  = (const float*)d_in[40];
  const float* nt1 = (const float*)d_in[41];
  const float* ct1 = (const float*)d_in[42];
  const float* ht1 = (const float*)d_in[43];
  const float* mt1 = (const float*)d_in[44];
  float* dout = (float*)d_out;

  char* ws = (char*)d_ws;
  size_t off = 0;
  auto alloc = [&](size_t n) { size_t o = off; off += (n + 255) & ~(size_t)255; return o; };

  const size_t SZ_WT   = 512ull*32768*2;   // 32 MB
  const size_t SZ_XPAD = 4ull*1087*512*2;  // 4.45 MB
  const size_t SZ_PART = 4096ull*512*4;    // 8 MB per split
  const size_t SZ_PRE  = 4ull*4096*512*4;  // 32 MB
  const size_t tail = (4*512*4 + 256) + 3*(512*512*4 + 256) + 6*4096;
  int S = (SZ_WT + SZ_XPAD + 4*SZ_PART + SZ_PRE + tail + 65536 <= ws_size) ? 4 : 2;

  const size_t o_wt   = alloc(SZ_WT);
  const size_t o_xpad = alloc(SZ_XPAD);
  const size_t o_part = alloc((size_t)S * SZ_PART);
  const size_t o_pre  = alloc(SZ_PRE);
  const size_t o_rv   = alloc(4*512*4);
  const size_t o_pct  = alloc(512*512*4);
  const size_t o_pnt  = alloc(512*512*4);
  const size_t o_pht  = alloc(512*512*4);
  const size_t o_r    = alloc(512*4);
  const size_t o_s    = alloc(512*4);
  const size_t o_lr   = alloc(682*4);
  const size_t o_g    = alloc(682*4);

  u16*   wt    = (u16*)(ws + o_wt);
  u16*   xpad  = (u16*)(ws + o_xpad);
  float* part  = (float*)(ws + o_part);
  float* pre   = (float*)(ws + o_pre);
  float* obuf  = part;                   // part is dead after k_bd
  float* rv    = (float*)(ws + o_rv);
  float* pct   = (float*)(ws + o_pct);
  float* pnt   = (float*)(ws + o_pnt);
  float* pht   = (float*)(ws + o_pht);
  float* rbuf  = (float*)(ws + o_r);
  float* svec  = (float*)(ws + o_s);
  float* lrbuf = (float*)(ws + o_lr);
  float* gbuf  = (float*)(ws + o_g);

  k_zero_pad<<<dim3(4, 63), 256, 0, stream>>>(xpad);
  k_cvt_w<<<dim3(512, 4), 256, 0, stream>>>(conv_w, wt);
  k_ln_x<<<4096, 256, 0, stream>>>(x, ln_g, ln_b, xpad);
  k_gemm<<<dim3(32, 4, S), 512, 0, stream>>>(wt, xpad, part, 512 / S);
  k_rvec<<<1, 256, 0, stream>>>(rwi, rwf, rwo, rwz, ht1, rv);
  k_bd<<<dim3(8, 64, 2), 256, 0, stream>>>(part, S, conv_b, xpad,
      wi, wf, wo, wz, bi, bf, bo, bz, rv, pre);
  k_gates2<<<512, 256, 0, stream>>>(pre,
      lni_g, lni_b, lnf_g, lnf_b, lno_g, lno_b, lnz_g, lnz_b,
      lnc_g, lnc_b, lnn_g, lnn_b, mt1, ct1, nt1,
      obuf, pct, pnt);
  k_r<<<1, 512, 0, stream>>>(pct, pnt, rbuf);
  k_ht<<<512, 256, 0, stream>>>(obuf, rbuf, lnh_g, lnh_b, pht);
  k_s<<<1, 512, 0, stream>>>(pht, gn_g, gn_b, svec);
  k_lr<<<682, 64, 0, stream>>>(svec, left_w, left_b, right_w, right_b, lrbuf);
  k_lnout<<<1, 256, 0, stream>>>(lrbuf, lnout_g, lnout_b, gbuf);
  k_proj<<<512, 64, 0, stream>>>(gbuf, proj_w, proj_b, dout);
}